// Round 1
// 2327.523 us; speedup vs baseline: 1.0848x; 1.0848x over previous
//
#include <hip/hip_runtime.h>
#include <hip/hip_bf16.h>
#include <stdint.h>

// Problem shape (fixed by reference)
#define B_DIM 2
#define S_DIM 2048
#define D_DIM 4096
#define V_DIM 32000
#define M_DIM (B_DIM * S_DIM)        // 4096 rows into the GEMM
#define OUT_ROWS (B_DIM * (S_DIM-1)) // 4094 output rows after shift

typedef __hip_bfloat16 bf16;
typedef __bf16 bf16x8 __attribute__((ext_vector_type(8)));
typedef float floatx4 __attribute__((ext_vector_type(4)));

// ---- async global->LDS (16B granules); LDS dst is wave-uniform base + lane*16
__device__ __forceinline__ void async16(const bf16* g, bf16* l) {
    __builtin_amdgcn_global_load_lds(
        (const __attribute__((address_space(1))) void*)g,
        (__attribute__((address_space(3))) void*)l,
        16, 0, 0);
}

// ---------------- RMSNorm + cast to bf16 ----------------
__global__ void rmsnorm_cast_kernel(const float* __restrict__ x,
                                    const float* __restrict__ w,
                                    bf16* __restrict__ h) {
    const int row = blockIdx.x;
    const int t = threadIdx.x;
    const float* xr = x + (size_t)row * D_DIM;

    float4 vals[4];
    float ss = 0.f;
#pragma unroll
    for (int i = 0; i < 4; ++i) {
        float4 v = ((const float4*)xr)[t + i * 256];
        vals[i] = v;
        ss += v.x * v.x + v.y * v.y + v.z * v.z + v.w * v.w;
    }
#pragma unroll
    for (int off = 32; off; off >>= 1) ss += __shfl_down(ss, off, 64);
    __shared__ float wsum[4];
    const int lane = t & 63, wv = t >> 6;
    if (lane == 0) wsum[wv] = ss;
    __syncthreads();
    const float var = (wsum[0] + wsum[1] + wsum[2] + wsum[3]) * (1.0f / D_DIM);
    const float scale = rsqrtf(var + 1e-6f);

    bf16* hr = h + (size_t)row * D_DIM;
#pragma unroll
    for (int i = 0; i < 4; ++i) {
        const int f4 = t + i * 256;
        float4 v = vals[i];
        float4 wv4 = ((const float4*)w)[f4];
        ushort4 pk;
        bf16 b0 = __float2bfloat16(v.x * scale * wv4.x);
        bf16 b1 = __float2bfloat16(v.y * scale * wv4.y);
        bf16 b2 = __float2bfloat16(v.z * scale * wv4.z);
        bf16 b3 = __float2bfloat16(v.w * scale * wv4.w);
        pk.x = *(unsigned short*)&b0;
        pk.y = *(unsigned short*)&b1;
        pk.z = *(unsigned short*)&b2;
        pk.w = *(unsigned short*)&b3;
        ((ushort4*)hr)[f4] = pk;
    }
}

// ---------------- W fp32 -> bf16 cast ----------------
__global__ void wcast_kernel(const float* __restrict__ W, bf16* __restrict__ Wb) {
    const size_t i = (size_t)blockIdx.x * 256 + threadIdx.x;
    float4 v = ((const float4*)W)[i];
    ushort4 pk;
    bf16 b0 = __float2bfloat16(v.x);
    bf16 b1 = __float2bfloat16(v.y);
    bf16 b2 = __float2bfloat16(v.z);
    bf16 b3 = __float2bfloat16(v.w);
    pk.x = *(unsigned short*)&b0;
    pk.y = *(unsigned short*)&b1;
    pk.z = *(unsigned short*)&b2;
    pk.w = *(unsigned short*)&b3;
    ((ushort4*)Wb)[i] = pk;
}

// ---------------- bf16 MFMA GEMM, 256x256 8-phase counted-vmcnt schedule ----------------
// C = A * B^T; A: h [4096][4096] bf16, B: Wb [32000][4096] bf16 (K-contiguous)
// 8 waves (2M x 4N), per-wave 128x64 out, BK=64 (2 k-subtiles), 2 K-tiles/iteration.
// LDS (bf16 elems): [db:2][mat:2 A,B][half:2][row:128][col:64] = 65536 elems = 128 KiB.
// XOR swizzle on element bits 3-5: read col (ks*32+quad*8)^((row&7)<<3); staged via
// inverse-swizzled GLOBAL source (linear LDS dest for global_load_lds).
#define BM 256
#define BN 256
#define BK 64

#define STAGE_A(db, half, kt) do { \
    const bf16* _g = aRow0 + (size_t)(half) * 128 * D_DIM + (kt) * BK; \
    bf16* _l = lds + (db) * 32768 + (half) * 8192 + t * 8; \
    async16(_g, _l); \
    async16(_g + (size_t)64 * D_DIM, _l + 4096); \
} while (0)

#define STAGE_B(db, half, kt) do { \
    const bf16* _g = bRow0 + (size_t)(half) * 128 * D_DIM + (kt) * BK; \
    bf16* _l = lds + (db) * 32768 + 16384 + (half) * 8192 + t * 8; \
    async16(_g, _l); \
    async16(_g + (size_t)64 * D_DIM, _l + 4096); \
} while (0)

#define LDA(db, mi, ks) (*(const bf16x8*)(lds + (db) * 32768 + aBase + (mi) * 1024 + ((ks) ? csw1 : csw0)))
#define LDB(db, ni, ks) (*(const bf16x8*)(lds + (db) * 32768 + bBase + (ni) * 1024 + ((ks) ? csw1 : csw0)))
#define MFMA(a, b, c) __builtin_amdgcn_mfma_f32_16x16x32_bf16((a), (b), (c), 0, 0, 0)
#define BAR() __builtin_amdgcn_s_barrier()
#define PRIO1() __builtin_amdgcn_s_setprio(1)
#define PRIO0() __builtin_amdgcn_s_setprio(0)

__global__ __launch_bounds__(512, 2) void gemm_kernel(const bf16* __restrict__ A,
                                                      const bf16* __restrict__ Bw,
                                                      float* __restrict__ Cout) {
    __shared__ __align__(16) bf16 lds[65536]; // 128 KiB

    // bijective XCD swizzle (2000 wgs, 2000 % 8 == 0), panel-major: 16 consecutive
    // wgs share one 256-row W panel -> each XCD streams ~2 panels at a time.
    const int bid = blockIdx.x;
    const int wg  = (bid & 7) * 250 + (bid >> 3);
    const int bm  = wg & 15;        // 16 M tiles
    const int bn  = wg >> 4;        // 125 N tiles
    const int m0  = bm * BM, n0 = bn * BN;

    const int t    = threadIdx.x;
    const int lane = t & 63;
    const int wv   = t >> 6;        // 8 waves
    const int wmi  = wv >> 2;       // 0..1 (M)
    const int wni  = wv & 3;        // 0..3 (N)
    const int quad = lane >> 4;
    const int l15  = lane & 15;

    // stage-side: thread t owns granules g=t and g=t+512 of each 16KB half-region.
    // row(g)=g>>3; source col pre-swizzled: ((g&7)^(row&7))*8 elements.
    const int r0 = t >> 3;                        // 0..63 (granule 1 adds +64 rows)
    const int c0 = ((t & 7) ^ (r0 & 7)) << 3;
    const bf16* aRow0 = A  + (size_t)(m0 + r0) * D_DIM + c0;
    const bf16* bRow0 = Bw + (size_t)(n0 + r0) * D_DIM + c0;

    // read-side swizzled column offsets (elements), row&7 == l15&7 for all frags
    const int vx   = (l15 & 7) << 3;
    const int csw0 = ((quad << 3)     ) ^ vx;     // k-subtile 0
    const int csw1 = ((quad << 3) | 32) ^ vx;     // k-subtile 1
    const int aBase = wmi * 8192 + l15 * 64;
    const int bBase = 16384 + (wni >> 1) * 8192 + (wni & 1) * 4096 + l15 * 64;

    floatx4 acc[8][4] = {};
    bf16x8 af[4][2], b01[2][2], b23[2][2];

    // ---- prologue: tile0 -> buf0, tile1 -> buf1 (issue order defines vmcnt ages)
    STAGE_B(0, 0, 0); STAGE_B(0, 1, 0); STAGE_A(0, 0, 0); STAGE_A(0, 1, 0);
    STAGE_B(1, 0, 1); STAGE_B(1, 1, 1); STAGE_A(1, 0, 1); STAGE_A(1, 1, 1);
    asm volatile("s_waitcnt vmcnt(8)" ::: "memory"); // tile0 landed; tile1 in flight
    BAR();

    for (int it = 0; it < 32; ++it) {
        // prefetch tiles; clamp keeps the last iteration's counts identical (data unused)
        int kta = 2 * it + 2; if (kta > 63) kta = 63;   // -> buf0
        int ktb = 2 * it + 3; if (ktb > 63) ktb = 63;   // -> buf1

#pragma unroll
        for (int db = 0; db < 2; ++db) {
            // ---- phase q0: read A m0-3 + B n0-1; MFMA quadrant [0..3][0..1]
#pragma unroll
            for (int mi = 0; mi < 4; ++mi) { af[mi][0] = LDA(db, mi, 0); af[mi][1] = LDA(db, mi, 1); }
#pragma unroll
            for (int ni = 0; ni < 2; ++ni) { b01[ni][0] = LDB(db, ni, 0); b01[ni][1] = LDB(db, ni, 1); }
            if (db == 1) STAGE_A(0, 0, kta);            // p5 (buf0.A reads done @p3)
            BAR();
            PRIO1();
#pragma unroll
            for (int mi = 0; mi < 4; ++mi)
#pragma unroll
                for (int ni = 0; ni < 2; ++ni) {
                    acc[mi][ni] = MFMA(af[mi][0], b01[ni][0], acc[mi][ni]);
                    acc[mi][ni] = MFMA(af[mi][1], b01[ni][1], acc[mi][ni]);
                }
            PRIO0();
            BAR();

            // ---- phase q1: read B n2-3; MFMA [0..3][2..3]
#pragma unroll
            for (int ni = 0; ni < 2; ++ni) { b23[ni][0] = LDB(db, ni + 2, 0); b23[ni][1] = LDB(db, ni + 2, 1); }
            if (db == 1) STAGE_A(0, 1, kta);            // p6
            BAR();
            PRIO1();
#pragma unroll
            for (int mi = 0; mi < 4; ++mi)
#pragma unroll
                for (int ni = 0; ni < 2; ++ni) {
                    acc[mi][ni + 2] = MFMA(af[mi][0], b23[ni][0], acc[mi][ni + 2]);
                    acc[mi][ni + 2] = MFMA(af[mi][1], b23[ni][1], acc[mi][ni + 2]);
                }
            PRIO0();
            BAR();

            // ---- phase q2: read A m4-7; MFMA [4..7][0..1]
#pragma unroll
            for (int mi = 0; mi < 4; ++mi) { af[mi][0] = LDA(db, mi + 4, 0); af[mi][1] = LDA(db, mi + 4, 1); }
            if (db == 0) { STAGE_B(0, 0, kta); }                      // p3 (buf0.B reads done @p2)
            else         { STAGE_B(1, 0, ktb); STAGE_B(1, 1, ktb); }  // p7 (buf1.B reads done @p6)
            BAR();
            PRIO1();
#pragma unroll
            for (int mi = 0; mi < 4; ++mi)
#pragma unroll
                for (int ni = 0; ni < 2; ++ni) {
                    acc[mi + 4][ni] = MFMA(af[mi][0], b01[ni][0], acc[mi + 4][ni]);
                    acc[mi + 4][ni] = MFMA(af[mi][1], b01[ni][1], acc[mi + 4][ni]);
                }
            PRIO0();
            BAR();

            // ---- phase q3: no reads; MFMA [4..7][2..3]; counted vmcnt once per K-tile
            if (db == 0) { STAGE_B(0, 1, kta); }                      // p4
            else         { STAGE_A(1, 0, ktb); STAGE_A(1, 1, ktb); }  // p8 (buf1.A reads done @p7)
            BAR();
            PRIO1();
#pragma unroll
            for (int mi = 0; mi < 4; ++mi)
#pragma unroll
                for (int ni = 0; ni < 2; ++ni) {
                    acc[mi + 4][ni + 2] = MFMA(af[mi][0], b23[ni][0], acc[mi + 4][ni + 2]);
                    acc[mi + 4][ni + 2] = MFMA(af[mi][1], b23[ni][1], acc[mi + 4][ni + 2]);
                }
            PRIO0();
            if (db == 0) { asm volatile("s_waitcnt vmcnt(4)" ::: "memory"); } // drain buf1 tile; p3,p4 fly
            else         { asm volatile("s_waitcnt vmcnt(8)" ::: "memory"); } // drain buf0 tile; p7,p8 fly
            BAR();
        }
    }

    // ---- epilogue: C/D layout col = lane&15 (n), row = quad*4 + reg (m); shifted store
    const int mbase = m0 + wmi * 128 + quad * 4;
    const int nbase = n0 + wni * 64 + l15;
#pragma unroll
    for (int mi = 0; mi < 8; ++mi) {
#pragma unroll
        for (int r = 0; r < 4; ++r) {
            const int m = mbase + mi * 16 + r;
            const int s = m & (S_DIM - 1);
            if (s == S_DIM - 1) continue; // shifted out
            float* cp = Cout + (size_t)((m >> 11) * (S_DIM - 1) + s) * V_DIM + nbase;
#pragma unroll
            for (int ni = 0; ni < 4; ++ni)
                cp[ni * 16] = acc[mi][ni][r];
        }
    }
}

// ---------------- shifted labels ----------------
__global__ void labels_kernel(const int* __restrict__ labels, float* __restrict__ out) {
    const int r = blockIdx.x * 256 + threadIdx.x;
    if (r >= OUT_ROWS) return;
    const int b = r / (S_DIM - 1);
    const int s = r % (S_DIM - 1);
    out[r] = (float)labels[b * S_DIM + s + 1];
}

extern "C" void kernel_launch(void* const* d_in, const int* in_sizes, int n_in,
                              void* d_out, int out_size, void* d_ws, size_t ws_size,
                              hipStream_t stream) {
    const float* x      = (const float*)d_in[0];
    const float* nw     = (const float*)d_in[1];
    const float* W      = (const float*)d_in[2];
    const int*   labels = (const int*)d_in[4];

    float* logits_out = (float*)d_out;                         // [4094][32000]
    float* labels_out = logits_out + (size_t)OUT_ROWS * V_DIM; // [4094]

    bf16* h  = (bf16*)d_ws;
    bf16* Wb = h + (size_t)M_DIM * D_DIM;

    rmsnorm_cast_kernel<<<M_DIM, 256, 0, stream>>>(x, nw, h);
    wcast_kernel<<<(int)((size_t)V_DIM * D_DIM / 4 / 256), 256, 0, stream>>>(W, Wb);
    gemm_kernel<<<(M_DIM / BM) * (V_DIM / BN), 512, 0, stream>>>(h, Wb, logits_out);
    labels_kernel<<<(OUT_ROWS + 255) / 256, 256, 0, stream>>>(labels, labels_out);
}

// Round 2
// 2071.461 us; speedup vs baseline: 1.2189x; 1.1236x over previous
//
#include <hip/hip_runtime.h>
#include <hip/hip_bf16.h>
#include <stdint.h>

// Problem shape (fixed by reference)
#define B_DIM 2
#define S_DIM 2048
#define D_DIM 4096
#define V_DIM 32000
#define M_DIM (B_DIM * S_DIM)        // 4096 rows into the GEMM
#define OUT_ROWS (B_DIM * (S_DIM-1)) // 4094 output rows after shift

typedef __hip_bfloat16 bf16;
typedef __bf16 bf16x8 __attribute__((ext_vector_type(8)));
typedef float floatx4 __attribute__((ext_vector_type(4)));

// ---- async global->LDS (16B granules); LDS dst is wave-uniform base + lane*16
__device__ __forceinline__ void async16(const bf16* g, bf16* l) {
    __builtin_amdgcn_global_load_lds(
        (const __attribute__((address_space(1))) void*)g,
        (__attribute__((address_space(3))) void*)l,
        16, 0, 0);
}

// ---------------- RMSNorm + cast to bf16 ----------------
__global__ void rmsnorm_cast_kernel(const float* __restrict__ x,
                                    const float* __restrict__ w,
                                    bf16* __restrict__ h) {
    const int row = blockIdx.x;
    const int t = threadIdx.x;
    const float* xr = x + (size_t)row * D_DIM;

    float4 vals[4];
    float ss = 0.f;
#pragma unroll
    for (int i = 0; i < 4; ++i) {
        float4 v = ((const float4*)xr)[t + i * 256];
        vals[i] = v;
        ss += v.x * v.x + v.y * v.y + v.z * v.z + v.w * v.w;
    }
#pragma unroll
    for (int off = 32; off; off >>= 1) ss += __shfl_down(ss, off, 64);
    __shared__ float wsum[4];
    const int lane = t & 63, wv = t >> 6;
    if (lane == 0) wsum[wv] = ss;
    __syncthreads();
    const float var = (wsum[0] + wsum[1] + wsum[2] + wsum[3]) * (1.0f / D_DIM);
    const float scale = rsqrtf(var + 1e-6f);

    bf16* hr = h + (size_t)row * D_DIM;
#pragma unroll
    for (int i = 0; i < 4; ++i) {
        const int f4 = t + i * 256;
        float4 v = vals[i];
        float4 wv4 = ((const float4*)w)[f4];
        ushort4 pk;
        bf16 b0 = __float2bfloat16(v.x * scale * wv4.x);
        bf16 b1 = __float2bfloat16(v.y * scale * wv4.y);
        bf16 b2 = __float2bfloat16(v.z * scale * wv4.z);
        bf16 b3 = __float2bfloat16(v.w * scale * wv4.w);
        pk.x = *(unsigned short*)&b0;
        pk.y = *(unsigned short*)&b1;
        pk.z = *(unsigned short*)&b2;
        pk.w = *(unsigned short*)&b3;
        ((ushort4*)hr)[f4] = pk;
    }
}

// ---------------- W fp32 -> bf16 cast ----------------
__global__ void wcast_kernel(const float* __restrict__ W, bf16* __restrict__ Wb) {
    const size_t i = (size_t)blockIdx.x * 256 + threadIdx.x;
    float4 v = ((const float4*)W)[i];
    ushort4 pk;
    bf16 b0 = __float2bfloat16(v.x);
    bf16 b1 = __float2bfloat16(v.y);
    bf16 b2 = __float2bfloat16(v.z);
    bf16 b3 = __float2bfloat16(v.w);
    pk.x = *(unsigned short*)&b0;
    pk.y = *(unsigned short*)&b1;
    pk.z = *(unsigned short*)&b2;
    pk.w = *(unsigned short*)&b3;
    ((ushort4*)Wb)[i] = pk;
}

// ---------------- bf16 MFMA GEMM, 256x256, asymmetric-depth counted-vmcnt pipeline ----------------
// C = A * B^T; A: h [4096][4096] bf16 (LLC-resident, ~500cy), B: Wb [32000][4096] bf16 (HBM stream, ~900cy)
// 8 waves (2M x 4N), per-wave 128x64 out, BK=64, 4 phases/K-tile.
// LDS: A ring-2 (64 KB) + B ring-3 (96 KB) = 160 KB exactly. 1 block/CU by design.
// Pipeline: tile j phase q3 issues A(j+2) then B(j+3); single vmcnt(12) per tile waits
// exactly for A(j+1)+B(j+1) -> A gets ~4-phase cover (LLC), B gets ~8-phase cover (HBM).
// XOR swizzle on element bits 3-5 (inverse-swizzled global src + swizzled ds_read).
#define BM 256
#define BN 256
#define BK 64
#define LDS_TILE 16384   // elems per (matrix, ring slot): [half:2][row:128][col:64]

// stage one full 256x64 tile (4 async16 per thread; rows r0, r0+64, r0+128, r0+192)
#define STAGE_A(slot, kt) do { \
    const bf16* _g = aRow0 + (size_t)(kt) * BK; \
    bf16* _l = ldsA + (slot) * LDS_TILE + t * 8; \
    async16(_g,                       _l); \
    async16(_g + (size_t) 64 * D_DIM, _l + 4096); \
    async16(_g + (size_t)128 * D_DIM, _l + 8192); \
    async16(_g + (size_t)192 * D_DIM, _l + 12288); \
} while (0)

#define STAGE_B(slot, kt) do { \
    const bf16* _g = bRow0 + (size_t)(kt) * BK; \
    bf16* _l = ldsB + (slot) * LDS_TILE + t * 8; \
    async16(_g,                       _l); \
    async16(_g + (size_t) 64 * D_DIM, _l + 4096); \
    async16(_g + (size_t)128 * D_DIM, _l + 8192); \
    async16(_g + (size_t)192 * D_DIM, _l + 12288); \
} while (0)

#define LDA(mi, ks) (*(const bf16x8*)(aT + (mi) * 1024 + aBase + ((ks) ? csw1 : csw0)))
#define LDB(ni, ks) (*(const bf16x8*)(bT + (ni) * 1024 + bBase + ((ks) ? csw1 : csw0)))
#define MFMA(a, b, c) __builtin_amdgcn_mfma_f32_16x16x32_bf16((a), (b), (c), 0, 0, 0)
#define BAR() __builtin_amdgcn_s_barrier()
#define PRIO1() __builtin_amdgcn_s_setprio(1)
#define PRIO0() __builtin_amdgcn_s_setprio(0)

__global__ __launch_bounds__(512, 2) void gemm_kernel(const bf16* __restrict__ A,
                                                      const bf16* __restrict__ Bw,
                                                      float* __restrict__ Cout) {
    __shared__ __align__(16) bf16 ldsA[2 * LDS_TILE]; // 64 KB, ring-2
    __shared__ __align__(16) bf16 ldsB[3 * LDS_TILE]; // 96 KB, ring-3

    // bijective XCD swizzle (2000 wgs % 8 == 0), N-panel-major: 16 consecutive wgs
    // on one XCD share one 256-row W panel (16x L2 reuse of B).
    const int bid = blockIdx.x;
    const int wg  = (bid & 7) * 250 + (bid >> 3);
    const int bm  = wg & 15;        // 16 M tiles
    const int bn  = wg >> 4;        // 125 N tiles
    const int m0  = bm * BM, n0 = bn * BN;

    const int t    = threadIdx.x;
    const int lane = t & 63;
    const int wv   = t >> 6;        // 8 waves
    const int wmi  = wv >> 2;       // 0..1 (M)
    const int wni  = wv & 3;        // 0..3 (N)
    const int quad = lane >> 4;
    const int l15  = lane & 15;

    // stage-side: thread t owns granule g=t of each 16KB half; row(g)=g>>3,
    // source col pre-swizzled: ((g&7)^(row&7))*8 elements (inverse of read swizzle).
    const int r0 = t >> 3;                        // 0..63 (further granules add +64 rows)
    const int c0 = ((t & 7) ^ (r0 & 7)) << 3;
    const bf16* aRow0 = A  + (size_t)(m0 + r0) * D_DIM + c0;
    const bf16* bRow0 = Bw + (size_t)(n0 + r0) * D_DIM + c0;

    // read-side swizzled column offsets (elements); row&7 == l15&7 for all frags
    const int vx   = (l15 & 7) << 3;
    const int csw0 = ((quad << 3)     ) ^ vx;     // k-subtile 0
    const int csw1 = ((quad << 3) | 32) ^ vx;     // k-subtile 1
    const int aBase = wmi * 8192 + l15 * 64;
    const int bBase = (wni >> 1) * 8192 + (wni & 1) * 4096 + l15 * 64;

    floatx4 acc[8][4] = {};
    bf16x8 af[4][2], b01[2][2], b23[2][2];

    // ---- prologue: emulate steady-state issue stream of tiles -3..-1:
    // B(0) [t-3], A(0),B(1) [t-2], A(1),B(2) [t-1]  (4 loads each, 20 total)
    STAGE_B(0, 0);
    STAGE_A(0, 0);
    STAGE_B(1, 1);
    STAGE_A(1, 1);
    STAGE_B(2, 2);
    asm volatile("s_waitcnt vmcnt(12)" ::: "memory"); // A(0),B(0) landed; 12 in flight
    BAR();

    int bs = 0; // B ring slot for tile j (= j % 3); A slot = j & 1
    for (int j = 0; j < 64; ++j) {
        const int as = j & 1;
        int ka = j + 2; if (ka > 63) ka = 63;  // dup-stage tail is WAR-safe, data unused
        int kb = j + 3; if (kb > 63) kb = 63;
        const bf16* aT = ldsA + as * LDS_TILE;
        const bf16* bT = ldsB + bs * LDS_TILE;

        // ---- q0: read A m0-3 (x2 ks) + B n0-1; MFMA [0..3][0..1]
#pragma unroll
        for (int mi = 0; mi < 4; ++mi) { af[mi][0] = LDA(mi, 0); af[mi][1] = LDA(mi, 1); }
#pragma unroll
        for (int ni = 0; ni < 2; ++ni) { b01[ni][0] = LDB(ni, 0); b01[ni][1] = LDB(ni, 1); }
        BAR();
        PRIO1();
#pragma unroll
        for (int mi = 0; mi < 4; ++mi)
#pragma unroll
            for (int ni = 0; ni < 2; ++ni) {
                acc[mi][ni] = MFMA(af[mi][0], b01[ni][0], acc[mi][ni]);
                acc[mi][ni] = MFMA(af[mi][1], b01[ni][1], acc[mi][ni]);
            }
        PRIO0();
        BAR();

        // ---- q1: read B n2-3; MFMA [0..3][2..3]   (B(j) reads complete here)
#pragma unroll
        for (int ni = 0; ni < 2; ++ni) { b23[ni][0] = LDB(ni + 2, 0); b23[ni][1] = LDB(ni + 2, 1); }
        BAR();
        PRIO1();
#pragma unroll
        for (int mi = 0; mi < 4; ++mi)
#pragma unroll
            for (int ni = 0; ni < 2; ++ni) {
                acc[mi][ni + 2] = MFMA(af[mi][0], b23[ni][0], acc[mi][ni + 2]);
                acc[mi][ni + 2] = MFMA(af[mi][1], b23[ni][1], acc[mi][ni + 2]);
            }
        PRIO0();
        BAR();

        // ---- q2: read A m4-7; MFMA [4..7][0..1]   (A(j) reads complete here)
#pragma unroll
        for (int mi = 0; mi < 4; ++mi) { af[mi][0] = LDA(mi + 4, 0); af[mi][1] = LDA(mi + 4, 1); }
        BAR();
        PRIO1();
#pragma unroll
        for (int mi = 0; mi < 4; ++mi)
#pragma unroll
            for (int ni = 0; ni < 2; ++ni) {
                acc[mi + 4][ni] = MFMA(af[mi][0], b01[ni][0], acc[mi + 4][ni]);
                acc[mi + 4][ni] = MFMA(af[mi][1], b01[ni][1], acc[mi + 4][ni]);
            }
        PRIO0();
        BAR();

        // ---- q3: stage A(j+2) then B(j+3) (WAR-safe: same-slot reads done q2/q1,
        // separated by >=2 barriers); MFMA [4..7][2..3]; counted drain vmcnt(12):
        // waits exactly for A(j+1) [4-phase cover, LLC] + B(j+1) [8-phase cover, HBM];
        // leaves B(j+2), A(j+2), B(j+3) = 12 loads in flight.
        STAGE_A(as, ka);
        STAGE_B(bs, kb);
        BAR();
        PRIO1();
#pragma unroll
        for (int mi = 0; mi < 4; ++mi)
#pragma unroll
            for (int ni = 0; ni < 2; ++ni) {
                acc[mi + 4][ni + 2] = MFMA(af[mi][0], b23[ni][0], acc[mi + 4][ni + 2]);
                acc[mi + 4][ni + 2] = MFMA(af[mi][1], b23[ni][1], acc[mi + 4][ni + 2]);
            }
        PRIO0();
        asm volatile("s_waitcnt vmcnt(12)" ::: "memory");
        BAR();

        bs = (bs == 2) ? 0 : bs + 1;
    }

    // ---- epilogue: C/D layout col = lane&15 (n), row = quad*4 + reg (m); shifted store
    const int mbase = m0 + wmi * 128 + quad * 4;
    const int nbase = n0 + wni * 64 + l15;
#pragma unroll
    for (int mi = 0; mi < 8; ++mi) {
#pragma unroll
        for (int r = 0; r < 4; ++r) {
            const int m = mbase + mi * 16 + r;
            const int s = m & (S_DIM - 1);
            if (s == S_DIM - 1) continue; // shifted out
            float* cp = Cout + (size_t)((m >> 11) * (S_DIM - 1) + s) * V_DIM + nbase;
#pragma unroll
            for (int ni = 0; ni < 4; ++ni)
                cp[ni * 16] = acc[mi][ni][r];
        }
    }
}

// ---------------- shifted labels ----------------
__global__ void labels_kernel(const int* __restrict__ labels, float* __restrict__ out) {
    const int r = blockIdx.x * 256 + threadIdx.x;
    if (r >= OUT_ROWS) return;
    const int b = r / (S_DIM - 1);
    const int s = r % (S_DIM - 1);
    out[r] = (float)labels[b * S_DIM + s + 1];
}

extern "C" void kernel_launch(void* const* d_in, const int* in_sizes, int n_in,
                              void* d_out, int out_size, void* d_ws, size_t ws_size,
                              hipStream_t stream) {
    const float* x      = (const float*)d_in[0];
    const float* nw     = (const float*)d_in[1];
    const float* W      = (const float*)d_in[2];
    const int*   labels = (const int*)d_in[4];

    float* logits_out = (float*)d_out;                         // [4094][32000]
    float* labels_out = logits_out + (size_t)OUT_ROWS * V_DIM; // [4094]

    bf16* h  = (bf16*)d_ws;
    bf16* Wb = h + (size_t)M_DIM * D_DIM;

    rmsnorm_cast_kernel<<<M_DIM, 256, 0, stream>>>(x, nw, h);
    wcast_kernel<<<(int)((size_t)V_DIM * D_DIM / 4 / 256), 256, 0, stream>>>(W, Wb);
    gemm_kernel<<<(M_DIM / BM) * (V_DIM / BN), 512, 0, stream>>>(h, Wb, logits_out);
    labels_kernel<<<(OUT_ROWS + 255) / 256, 256, 0, stream>>>(labels, labels_out);
}